// Round 1
// baseline (5916.286 us; speedup 1.0000x reference)
//
#include <hip/hip_runtime.h>

#define T_ 2048
#define B_ 128
#define IN_ 64
#define H_ 128
#define G_ 512   // 4*H
#define OUT_ 32

typedef _Float16 h2_t __attribute__((ext_vector_type(2)));
union HU { unsigned u; h2_t h; };

__device__ __forceinline__ float fdot2u(unsigned a, unsigned b, float c) {
  HU x, y; x.u = a; y.u = b;
  return __builtin_amdgcn_fdot2(x.h, y.h, c, false);
}
__device__ __forceinline__ unsigned packf2(float a, float b) {
  HU u; u.h.x = (_Float16)a; u.h.y = (_Float16)b; return u.u;
}
__device__ __forceinline__ float sigm(float x) { return 1.0f / (1.0f + __expf(-x)); }
__device__ __forceinline__ float tanh_f(float x) { return 1.0f - 2.0f / (1.0f + __expf(2.0f * x)); }

__global__ __launch_bounds__(512, 2) void lstm_fused(
    const float* __restrict__ x, const float* __restrict__ w_ih0,
    const float* __restrict__ w_hh0, const float* __restrict__ w_ih1,
    const float* __restrict__ w_hh1, const float* __restrict__ fc_w,
    const float* __restrict__ fc_b, float* __restrict__ out)
{
  const int tid = threadIdx.x;
  const int b = blockIdx.x;

  __shared__ unsigned sh_x[IN_ / 2];    // x_t as f16 pairs
  __shared__ unsigned sh_h0[H_ / 2];    // h of layer 0, f16 pairs
  __shared__ unsigned sh_h1[H_ / 2];    // h of layer 1, f16 pairs
  __shared__ float    sh_act[G_];       // gate activations fp32

  // ---- preload weights into registers as packed f16 pairs (gate-row per thread) ----
  unsigned wih0r[IN_ / 2], whh0r[H_ / 2], wih1r[H_ / 2], whh1r[H_ / 2], fcwr[4];
  {
    const float4* p = (const float4*)(w_ih0 + (size_t)tid * IN_);
#pragma unroll
    for (int q = 0; q < IN_ / 4; ++q) {
      float4 v = p[q];
      wih0r[2 * q] = packf2(v.x, v.y); wih0r[2 * q + 1] = packf2(v.z, v.w);
    }
  }
  {
    const float4* p = (const float4*)(w_hh0 + (size_t)tid * H_);
#pragma unroll
    for (int q = 0; q < H_ / 4; ++q) {
      float4 v = p[q];
      whh0r[2 * q] = packf2(v.x, v.y); whh0r[2 * q + 1] = packf2(v.z, v.w);
    }
  }
  {
    const float4* p = (const float4*)(w_ih1 + (size_t)tid * H_);
#pragma unroll
    for (int q = 0; q < H_ / 4; ++q) {
      float4 v = p[q];
      wih1r[2 * q] = packf2(v.x, v.y); wih1r[2 * q + 1] = packf2(v.z, v.w);
    }
  }
  {
    const float4* p = (const float4*)(w_hh1 + (size_t)tid * H_);
#pragma unroll
    for (int q = 0; q < H_ / 4; ++q) {
      float4 v = p[q];
      whh1r[2 * q] = packf2(v.x, v.y); whh1r[2 * q + 1] = packf2(v.z, v.w);
    }
  }
  const int o_idx = tid >> 4;   // FC output index 0..31
  const int seg   = tid & 15;   // 8-element segment of the 128-dot
  {
    const float4* p = (const float4*)(fc_w + (size_t)o_idx * H_ + seg * 8);
    float4 v0 = p[0], v1 = p[1];
    fcwr[0] = packf2(v0.x, v0.y); fcwr[1] = packf2(v0.z, v0.w);
    fcwr[2] = packf2(v1.x, v1.y); fcwr[3] = packf2(v1.z, v1.w);
  }
  const float fcb = fc_b[o_idx];

  // ---- state init ----
  float c0x = 0.f, c0y = 0.f, c1x = 0.f, c1y = 0.f;
  if (tid < H_ / 2) { sh_h0[tid] = 0u; sh_h1[tid] = 0u; }

  float2 xb = make_float2(0.f, 0.f);
  if (tid < IN_ / 2) xb = ((const float2*)(x + (size_t)b * IN_))[tid];

  float* outp = out + (size_t)b * OUT_;
  const size_t base_hn = (size_t)T_ * B_ * OUT_;

#pragma unroll 1
  for (int t = 0; t < T_; ++t) {
    // stage x_t (prefetched last iter), then prefetch x_{t+1}
    if (tid < IN_ / 2) sh_x[tid] = packf2(xb.x, xb.y);
    __syncthreads();
    if (tid < IN_ / 2 && t + 1 < T_)
      xb = ((const float2*)(x + ((size_t)(t + 1) * B_ + b) * IN_))[tid];

    // ---- layer 0 gates: w_ih0 @ x_t + w_hh0 @ h0 ----
    {
      float a0 = 0.f, a1 = 0.f, a2 = 0.f, a3 = 0.f;
      const uint4* xv = (const uint4*)sh_x;
#pragma unroll
      for (int q = 0; q < IN_ / 8; ++q) {
        uint4 v = xv[q];
        a0 = fdot2u(wih0r[4 * q + 0], v.x, a0);
        a1 = fdot2u(wih0r[4 * q + 1], v.y, a1);
        a2 = fdot2u(wih0r[4 * q + 2], v.z, a2);
        a3 = fdot2u(wih0r[4 * q + 3], v.w, a3);
      }
      const uint4* hv = (const uint4*)sh_h0;
#pragma unroll
      for (int q = 0; q < H_ / 8; ++q) {
        uint4 v = hv[q];
        a0 = fdot2u(whh0r[4 * q + 0], v.x, a0);
        a1 = fdot2u(whh0r[4 * q + 1], v.y, a1);
        a2 = fdot2u(whh0r[4 * q + 2], v.z, a2);
        a3 = fdot2u(whh0r[4 * q + 3], v.w, a3);
      }
      float a = (a0 + a1) + (a2 + a3);
      // gate regions (128 rows each): i,f sigmoid; g tanh; o sigmoid — wave-uniform branch
      sh_act[tid] = (tid >= 2 * H_ && tid < 3 * H_) ? tanh_f(a) : sigm(a);
    }
    __syncthreads();

    // ---- layer 0 state update (threads 0..63 own columns 2j, 2j+1) ----
    if (tid < H_ / 2) {
      float2 iv = ((const float2*)(sh_act + 0 * H_))[tid];
      float2 fv = ((const float2*)(sh_act + 1 * H_))[tid];
      float2 gv = ((const float2*)(sh_act + 2 * H_))[tid];
      float2 ov = ((const float2*)(sh_act + 3 * H_))[tid];
      c0x = fv.x * c0x + iv.x * gv.x;
      c0y = fv.y * c0y + iv.y * gv.y;
      sh_h0[tid] = packf2(ov.x * tanh_f(c0x), ov.y * tanh_f(c0y));
    }
    __syncthreads();

    // ---- layer 1 gates: w_ih1 @ h0 + w_hh1 @ h1 ----
    {
      float a0 = 0.f, a1 = 0.f, a2 = 0.f, a3 = 0.f;
      const uint4* hv0 = (const uint4*)sh_h0;
#pragma unroll
      for (int q = 0; q < H_ / 8; ++q) {
        uint4 v = hv0[q];
        a0 = fdot2u(wih1r[4 * q + 0], v.x, a0);
        a1 = fdot2u(wih1r[4 * q + 1], v.y, a1);
        a2 = fdot2u(wih1r[4 * q + 2], v.z, a2);
        a3 = fdot2u(wih1r[4 * q + 3], v.w, a3);
      }
      const uint4* hv1 = (const uint4*)sh_h1;
#pragma unroll
      for (int q = 0; q < H_ / 8; ++q) {
        uint4 v = hv1[q];
        a0 = fdot2u(whh1r[4 * q + 0], v.x, a0);
        a1 = fdot2u(whh1r[4 * q + 1], v.y, a1);
        a2 = fdot2u(whh1r[4 * q + 2], v.z, a2);
        a3 = fdot2u(whh1r[4 * q + 3], v.w, a3);
      }
      float a = (a0 + a1) + (a2 + a3);
      sh_act[tid] = (tid >= 2 * H_ && tid < 3 * H_) ? tanh_f(a) : sigm(a);
    }
    __syncthreads();

    // ---- layer 1 state update ----
    if (tid < H_ / 2) {
      float2 iv = ((const float2*)(sh_act + 0 * H_))[tid];
      float2 fv = ((const float2*)(sh_act + 1 * H_))[tid];
      float2 gv = ((const float2*)(sh_act + 2 * H_))[tid];
      float2 ov = ((const float2*)(sh_act + 3 * H_))[tid];
      c1x = fv.x * c1x + iv.x * gv.x;
      c1y = fv.y * c1y + iv.y * gv.y;
      sh_h1[tid] = packf2(ov.x * tanh_f(c1x), ov.y * tanh_f(c1y));
    }
    __syncthreads();

    // ---- FC head: out[t,b,o] = fc_w[o,:] @ h1 + fc_b[o]; 16 lanes per output ----
    {
      uint4 v = ((const uint4*)sh_h1)[seg];
      float p = fdot2u(fcwr[0], v.x, 0.0f);
      p = fdot2u(fcwr[1], v.y, p);
      p = fdot2u(fcwr[2], v.z, p);
      p = fdot2u(fcwr[3], v.w, p);
      p += __shfl_down(p, 8, 16);
      p += __shfl_down(p, 4, 16);
      p += __shfl_down(p, 2, 16);
      p += __shfl_down(p, 1, 16);
      if (seg == 0) outp[(size_t)t * B_ * OUT_ + o_idx] = p + fcb;
    }
  }

  // ---- final states: h_n [2,B,H] then c_n [2,B,H] ----
  if (tid < H_ / 2) {
    HU u0; u0.u = sh_h0[tid];
    HU u1; u1.u = sh_h1[tid];
    float* hn = out + base_hn;
    ((float2*)(hn + (size_t)b * H_))[tid] = make_float2((float)u0.h.x, (float)u0.h.y);
    ((float2*)(hn + (size_t)B_ * H_ + (size_t)b * H_))[tid] = make_float2((float)u1.h.x, (float)u1.h.y);
    float* cn = out + base_hn + 2 * (size_t)B_ * H_;
    ((float2*)(cn + (size_t)b * H_))[tid] = make_float2(c0x, c0y);
    ((float2*)(cn + (size_t)B_ * H_ + (size_t)b * H_))[tid] = make_float2(c1x, c1y);
  }
}

extern "C" void kernel_launch(void* const* d_in, const int* in_sizes, int n_in,
                              void* d_out, int out_size, void* d_ws, size_t ws_size,
                              hipStream_t stream) {
  const float* x     = (const float*)d_in[0];
  const float* w_ih0 = (const float*)d_in[1];
  const float* w_hh0 = (const float*)d_in[2];
  const float* w_ih1 = (const float*)d_in[3];
  const float* w_hh1 = (const float*)d_in[4];
  const float* fc_w  = (const float*)d_in[5];
  const float* fc_b  = (const float*)d_in[6];
  lstm_fused<<<B_, 512, 0, stream>>>(x, w_ih0, w_hh0, w_ih1, w_hh1, fc_w, fc_b,
                                     (float*)d_out);
}